// Round 12
// baseline (43.640 us; speedup 1.0000x reference)
//
#include <hip/hip_runtime.h>

#define B_ 64
#define T_ 4096
#define K_ 32
#define C_ 128
#define L_ 32
#define W_ 32            // W=16 -> absmax 1.56 (boundary); W=32 -> at 0.0625 floor
#define NPH 32           // 32 phases x 2 steps = 64 steps per direction

typedef float f32x16 __attribute__((ext_vector_type(16)));
typedef float f32x4v __attribute__((ext_vector_type(4)));
typedef short s16x8 __attribute__((ext_vector_type(8)));

union W4 { unsigned u[4]; short s[8]; s16x8 v; };

__device__ __forceinline__ unsigned cvt_pk_bf16(float lo, float hi) {
  unsigned r;
  asm("v_cvt_pk_bf16_f32 %0, %1, %2" : "=v"(r) : "v"(lo), "v"(hi));
  return r;
}
__device__ __forceinline__ short f2bf(float x) {  // RNE f32->bf16
  unsigned u = __float_as_uint(x);
  return (short)((u + 0x7FFFu + ((u >> 16) & 1u)) >> 16);
}
__device__ __forceinline__ float wmax32(float v) {
#pragma unroll
  for (int k = 16; k >= 1; k >>= 1) v = fmaxf(v, __shfl_xor(v, k, 32));
  return v;
}
__device__ __forceinline__ float wsum32(float v) {
#pragma unroll
  for (int k = 16; k >= 1; k >>= 1) v += __shfl_xor(v, k, 32);
  return v;
}
// async global->LDS DMA, 16B/lane; dest = lds base + lane*16 (HW), tracked by vmcnt
__device__ __forceinline__ void gload_lds16(const unsigned* g, unsigned* s) {
  __builtin_amdgcn_global_load_lds(
      (const __attribute__((address_space(1))) unsigned*)g,
      (__attribute__((address_space(3))) unsigned*)s, 16, 0, 0);
}

// Pass 1: pe = exp(em) -> CONTIGUOUS-per-lane bf16-pair layout, XCD-affine t.
// peP word = t*1024 + h*512 + b*8 + w ; value = pack(pe[b][t][s0], pe[b][t][s0+1]),
// s0 = 2*(w&1) + 8*(w>>1) + 4*h. Each scan lane's 8 words are one 32B run.
// Last block (bid==T_) does softmax prep into eA/lp.
__global__ __launch_bounds__(256) void pet_kernel(const float* __restrict__ em,
                                                  const float* __restrict__ log_pi,
                                                  const float* __restrict__ log_A,
                                                  float* __restrict__ eA,
                                                  float* __restrict__ lp,
                                                  unsigned* __restrict__ peP) {
  const int bid = (int)blockIdx.x;
  const int tid = (int)threadIdx.x;
  if (bid >= T_) {
    const int i0 = tid >> 5, j = tid & 31;
#pragma unroll
    for (int rr = 0; rr < 4; ++rr) {
      int i = i0 + 8 * rr;
      float a = log_A[i * K_ + j];
      float m = wmax32(a);
      float e = __expf(a - m);
      float S = wsum32(e);
      eA[i * K_ + j] = e / S;
    }
    if (i0 == 0) {
      float v = log_pi[j];
      float m2 = wmax32(v);
      float ee = __expf(v - m2);
      float SS = wsum32(ee);
      lp[j] = v - m2 - __logf(SS);
    }
    return;
  }
  const int t = ((bid & 7) << 9) + (bid >> 3);  // XCD-affinity permutation
  __shared__ float tile[K_][65];                // padded
  const int b = tid >> 2, kq = tid & 3;
  const float* p = em + (size_t)b * (T_ * K_) + (size_t)t * K_ + kq * 8;
  f32x4v v0 = *(const f32x4v*)p;
  f32x4v v1 = *(const f32x4v*)(p + 4);
#pragma unroll
  for (int q = 0; q < 4; ++q) tile[kq * 8 + q][b] = __expf(v0[q]);
#pragma unroll
  for (int q = 0; q < 4; ++q) tile[kq * 8 + 4 + q][b] = __expf(v1[q]);
  __syncthreads();
  unsigned* ob = peP + (size_t)t * 1024;
#pragma unroll
  for (int rr = 0; rr < 4; ++rr) {
    int W2 = tid + 256 * rr;
    int bb = (W2 >> 3) & 63, w = W2 & 7, hh = W2 >> 9;
    int s0 = 2 * (w & 1) + 8 * (w >> 1) + 4 * hh;
    ob[W2] = cvt_pk_bf16(tile[s0][bb], tile[s0 + 1][bb]);
  }
}

// Pass 2: one block per (group, chunk). 128 threads: wave0 = fwd scan, wave1 =
// bwd scan. pe staged via global_load_lds into per-direction double-buffered
// LDS (2-step phases), counted s_waitcnt vmcnt(4) at each phase top (T3/T4).
// The scan loop contains NO other VMEM ops (einit preloaded) so the hand count
// is exact. 144 KB LDS total.
__global__ __launch_bounds__(128) void hmm2_kernel(const unsigned* __restrict__ peP,
                                                   const float* __restrict__ eA,
                                                   const float* __restrict__ lp,
                                                   float* __restrict__ out) {
  __shared__ __align__(16) unsigned aw[L_ * 512];  // 64 KB alpha (bf16 pairs)
  __shared__ __align__(16) unsigned bw[L_ * 512];  // 64 KB beta~
  __shared__ __align__(16) unsigned peb[4096];     // 16 KB: [dir][buf][step][run]
  const int bid = (int)blockIdx.x;
  const int c = ((bid & 7) << 4) + ((bid >> 3) & 15);  // XCD-affine chunk
  const int g = bid >> 7;
  const int tid = (int)threadIdx.x;
  const int wv = tid >> 6;
  const int l = tid & 63;
  const int h = l >> 5;
  const int m = l & 31;  // batch (B/C col) or state (A operand row)
  const int t0 = c * L_;

  unsigned* myped = &peb[wv * 2048];
  const unsigned* psrc = peP + (g << 8) + (l << 2);  // + t*1024 (+512 for run 1)

  f32x16 zk;
#pragma unroll
  for (int r = 0; r < 16; ++r) zk[r] = 0.0f;

  W4 A1u, A2u, B1u, B2u;
#pragma unroll
  for (int r = 0; r < 8; ++r) {
    const int k1 = (r & 3) + 8 * (r >> 2) + 4 * h;
    const int k2 = k1 + 16;
    float a1 = (wv == 0) ? eA[k1 * K_ + m] : eA[m * K_ + k1];  // fwd: E^T, bwd: A
    float a2 = (wv == 0) ? eA[k2 * K_ + m] : eA[m * K_ + k2];
    A1u.s[r] = f2bf(a1);
    A2u.s[r] = f2bf(a2);
  }
#pragma unroll
  for (int q = 0; q < 4; ++q) { B1u.u[q] = 0x3F803F80u; B2u.u[q] = 0x3F803F80u; }

  // exp(log_softmax(pi)) preloaded: only fwd waves of chunks 0,1 ever hit t==0.
  float einit[16];
  if (wv == 0 && c < 2) {
#pragma unroll
    for (int r = 0; r < 16; ++r) einit[r] = __expf(lp[(r & 3) + 8 * (r >> 2) + 4 * h]);
  } else {
#pragma unroll
    for (int r = 0; r < 16; ++r) einit[r] = 0.0f;
  }

  // drain all prologue VMEM so the in-loop vmcnt count is exact
  asm volatile("s_waitcnt vmcnt(0)" ::: "memory");
  __builtin_amdgcn_sched_barrier(0);

#define ISSUE(PH, FWD)                                                         \
  if ((PH) < NPH) {                                                            \
    _Pragma("unroll") for (int s2 = 0; s2 < 2; ++s2) {                         \
      int SS = (PH) * 2 + s2;                                                  \
      int tt = (FWD) ? (t0 - W_ + SS) : (t0 + L_ - 1 + W_ - SS);               \
      tt = tt < 0 ? 0 : (tt > T_ - 1 ? T_ - 1 : tt);                           \
      const unsigned* sb = psrc + (size_t)tt * 1024;                           \
      unsigned* db = myped + (((PH) & 1) << 10) + (s2 << 9);                   \
      gload_lds16(sb, db);                                                     \
      gload_lds16(sb + 512, db + 256);                                         \
    }                                                                          \
  }

#define FSTEP(S)                                                               \
  {                                                                            \
    const int t = t0 + ((S) - W_);                                             \
    const unsigned* rp = myped + ((((S) >> 1) & 1) << 10) + (((S) & 1) << 9) + h * 256 + m * 8; \
    uint4 r0 = *(const uint4*)rp;                                              \
    uint4 r1 = *(const uint4*)(rp + 4);                                        \
    f32x16 acc = __builtin_amdgcn_mfma_f32_32x32x16_bf16(A1u.v, B1u.v, zk, 0, 0, 0); \
    acc = __builtin_amdgcn_mfma_f32_32x32x16_bf16(A2u.v, B2u.v, acc, 0, 0, 0); \
    if (t == 0) { /* exact init: alpha_0 = pi (pe applied below) */            \
      _Pragma("unroll") for (int r = 0; r < 16; ++r) acc[r] = einit[r];        \
    }                                                                          \
    unsigned rg[8];                                                            \
    rg[0] = r0.x; rg[1] = r0.y; rg[2] = r0.z; rg[3] = r0.w;                    \
    rg[4] = r1.x; rg[5] = r1.y; rg[6] = r1.z; rg[7] = r1.w;                    \
    float al[16];                                                              \
    _Pragma("unroll") for (int w = 0; w < 8; ++w) {                            \
      al[2 * w]     = acc[2 * w]     * __uint_as_float(rg[w] << 16);           \
      al[2 * w + 1] = acc[2 * w + 1] * __uint_as_float(rg[w] & 0xFFFF0000u);   \
    }                                                                          \
    if (((S) & 7) == 7) {                                                      \
      float a0 = __shfl(al[0], m, 64);                                         \
      float rs = __builtin_amdgcn_rcpf(a0);                                    \
      _Pragma("unroll") for (int r = 0; r < 16; ++r) al[r] *= rs;              \
    }                                                                          \
    W4 nB1, nB2;                                                               \
    _Pragma("unroll") for (int q = 0; q < 4; ++q) {                            \
      nB1.u[q] = cvt_pk_bf16(al[2 * q], al[2 * q + 1]);                        \
      nB2.u[q] = cvt_pk_bf16(al[8 + 2 * q], al[8 + 2 * q + 1]);                \
    }                                                                          \
    if ((S) >= W_) {                                                           \
      unsigned* bp = &aw[(((S) - W_) << 9) + h * 32 + m];                      \
      _Pragma("unroll") for (int q = 0; q < 4; ++q) {                          \
        bp[q * 64] = nB1.u[q];                                                 \
        bp[(4 + q) * 64] = nB2.u[q];                                           \
      }                                                                        \
    }                                                                          \
    B1u = nB1; B2u = nB2;                                                      \
  }

#define BSTEP(S)                                                               \
  {                                                                            \
    const int t = t0 + (L_ - 1 + W_ - (S));                                    \
    const unsigned* rp = myped + ((((S) >> 1) & 1) << 10) + (((S) & 1) << 9) + h * 256 + m * 8; \
    uint4 r0 = *(const uint4*)rp;                                              \
    uint4 r1 = *(const uint4*)(rp + 4);                                        \
    f32x16 acc = __builtin_amdgcn_mfma_f32_32x32x16_bf16(A1u.v, B1u.v, zk, 0, 0, 0); \
    acc = __builtin_amdgcn_mfma_f32_32x32x16_bf16(A2u.v, B2u.v, acc, 0, 0, 0); \
    if (t == T_ - 1) { /* exact init: beta_{T-1} = 1 */                        \
      _Pragma("unroll") for (int r = 0; r < 16; ++r) acc[r] = 1.0f;            \
    }                                                                          \
    if ((S) >= W_) {                                                           \
      W4 s1, s2;                                                               \
      _Pragma("unroll") for (int q = 0; q < 4; ++q) {                          \
        s1.u[q] = cvt_pk_bf16(acc[2 * q], acc[2 * q + 1]);                     \
        s2.u[q] = cvt_pk_bf16(acc[8 + 2 * q], acc[8 + 2 * q + 1]);             \
      }                                                                        \
      unsigned* bp = &bw[((L_ - 1 + W_ - (S)) << 9) + h * 32 + m];             \
      _Pragma("unroll") for (int q = 0; q < 4; ++q) {                          \
        bp[q * 64] = s1.u[q];                                                  \
        bp[(4 + q) * 64] = s2.u[q];                                            \
      }                                                                        \
    }                                                                          \
    unsigned rg[8];                                                            \
    rg[0] = r0.x; rg[1] = r0.y; rg[2] = r0.z; rg[3] = r0.w;                    \
    rg[4] = r1.x; rg[5] = r1.y; rg[6] = r1.z; rg[7] = r1.w;                    \
    float al[16];                                                              \
    _Pragma("unroll") for (int w = 0; w < 8; ++w) {                            \
      al[2 * w]     = acc[2 * w]     * __uint_as_float(rg[w] << 16);           \
      al[2 * w + 1] = acc[2 * w + 1] * __uint_as_float(rg[w] & 0xFFFF0000u);   \
    }                                                                          \
    if (((S) & 7) == 7) {                                                      \
      float a0 = __shfl(al[0], m, 64);                                         \
      float rs = __builtin_amdgcn_rcpf(a0);                                    \
      _Pragma("unroll") for (int r = 0; r < 16; ++r) al[r] *= rs;              \
    }                                                                          \
    W4 nB1, nB2;                                                               \
    _Pragma("unroll") for (int q = 0; q < 4; ++q) {                            \
      nB1.u[q] = cvt_pk_bf16(al[2 * q], al[2 * q + 1]);                        \
      nB2.u[q] = cvt_pk_bf16(al[8 + 2 * q], al[8 + 2 * q + 1]);                \
    }                                                                          \
    B1u = nB1; B2u = nB2;                                                      \
  }

  // counted-vmcnt phase: wait for this phase's 4 DMA loads (2 phases in
  // flight), consume 2 steps from LDS, then refill the freed buffer.
#define PHASE(PH, STEPM, FWD)                                                  \
  {                                                                            \
    asm volatile("s_waitcnt vmcnt(%0)" :: "i"((PH) < NPH - 1 ? 4 : 0) : "memory"); \
    __builtin_amdgcn_sched_barrier(0);                                         \
    STEPM((PH) * 2 + 0)                                                        \
    STEPM((PH) * 2 + 1)                                                        \
    __builtin_amdgcn_sched_barrier(0);                                         \
    ISSUE((PH) + 2, FWD)                                                       \
  }

#define PH8(A, STEPM, FWD)                                                     \
  PHASE((A) + 0, STEPM, FWD) PHASE((A) + 1, STEPM, FWD)                        \
  PHASE((A) + 2, STEPM, FWD) PHASE((A) + 3, STEPM, FWD)                        \
  PHASE((A) + 4, STEPM, FWD) PHASE((A) + 5, STEPM, FWD)                        \
  PHASE((A) + 6, STEPM, FWD) PHASE((A) + 7, STEPM, FWD)

  if (wv == 0) {
    ISSUE(0, 1) ISSUE(1, 1)
    PH8(0, FSTEP, 1) PH8(8, FSTEP, 1) PH8(16, FSTEP, 1) PH8(24, FSTEP, 1)
  } else {
    ISSUE(0, 0) ISSUE(1, 0)
    PH8(0, BSTEP, 0) PH8(8, BSTEP, 0) PH8(16, BSTEP, 0) PH8(24, BSTEP, 0)
  }

  __syncthreads();

  // ===== combine (2 waves x 16 rows): gamma = log(a*b) - log(sum_j a*b) =====
  {
#pragma unroll
    for (int rr = 0; rr < 16; ++rr) {
      const int row = (wv << 4) + rr;
      const unsigned* pa = aw + (row << 9) + (h << 5) + m;
      const unsigned* pb = bw + (row << 9) + (h << 5) + m;
      float gg[16];
      float s = 0.0f;
#pragma unroll
      for (int w = 0; w < 8; ++w) {
        unsigned ua = pa[w * 64], ub = pb[w * 64];
        gg[2 * w]     = __uint_as_float(ua << 16) * __uint_as_float(ub << 16);
        gg[2 * w + 1] = __uint_as_float(ua & 0xFFFF0000u) * __uint_as_float(ub & 0xFFFF0000u);
      }
#pragma unroll
      for (int r = 0; r < 16; ++r) s += gg[r];
      s += __shfl_xor(s, 32, 64);
      const float ls = __log2f(s);
      float* po = out + (size_t)((g << 5) + m) * (T_ * K_) + (size_t)(t0 + row) * K_;
#pragma unroll
      for (int w = 0; w < 8; ++w) {
        const int k0 = 2 * (w & 1) + 8 * (w >> 1) + 4 * h;
        float2 v;
        v.x = (__log2f(gg[2 * w]) - ls) * 0.6931471805599453f;
        v.y = (__log2f(gg[2 * w + 1]) - ls) * 0.6931471805599453f;
        *(float2*)(po + k0) = v;
      }
    }
  }
}

extern "C" void kernel_launch(void* const* d_in, const int* in_sizes, int n_in,
                              void* d_out, int out_size, void* d_ws, size_t ws_size,
                              hipStream_t stream) {
  const float* em = (const float*)d_in[0];      // [B,T,K] f32
  const float* log_pi = (const float*)d_in[1];  // [K] f32
  const float* log_A = (const float*)d_in[2];   // [K,K] f32
  float* out = (float*)d_out;                   // [B,T,K] f32

  float* eA = (float*)d_ws;                          // 1024 f32
  float* lp = eA + K_ * K_;                          // 32 f32
  unsigned* peP = (unsigned*)((char*)d_ws + 8192);   // 16 MB contiguous-layout pe

  pet_kernel<<<T_ + 1, 256, 0, stream>>>(em, log_pi, log_A, eA, lp, peP);
  hmm2_kernel<<<2 * C_, 128, 0, stream>>>(peP, eA, lp, out);
}